// Round 3
// baseline (565.931 us; speedup 1.0000x reference)
//
#include <hip/hip_runtime.h>

namespace {

typedef __attribute__((ext_vector_type(8))) short short8;   // 8 bf16 (MFMA A/B frag)
typedef __attribute__((ext_vector_type(4))) float f32x4;    // MFMA C/D frag
typedef __attribute__((ext_vector_type(4))) unsigned int uint4v;

constexpr int kH = 512, kW = 512, kB = 16, kC = 8;
constexpr int kHW = kH * kW;
constexpr int kBS = kC * kHW;
constexpr int TW = 64, TH = 4;
constexpr int TWP = TW + 2, THP = TH + 2;

// ---------------- kernel 1: global alive count ----------------
__global__ __launch_bounds__(256)
void alive_count_kernel(const float* __restrict__ x, int* __restrict__ cnt) {
    __shared__ int sdata[4];
    const int tid = threadIdx.x;
    const int total4 = kB * kHW / 4;
    int idx = blockIdx.x * 256 + tid;
    const int stride = gridDim.x * 256;
    int local = 0;
    const float4* x4 = (const float4*)x;
    for (int i = idx; i < total4; i += stride) {
        int b = i >> 16;
        int off = i & 65535;
        float4 v = x4[(size_t)b * (kBS / 4) + (3 * kHW / 4) + off];
        local += (v.x > 0.1f) + (v.y > 0.1f) + (v.z > 0.1f) + (v.w > 0.1f);
    }
    for (int off = 32; off > 0; off >>= 1)
        local += __shfl_down(local, off, 64);
    if ((tid & 63) == 0) sdata[tid >> 6] = local;
    __syncthreads();
    if (tid == 0) atomicAdd(cnt, sdata[0] + sdata[1] + sdata[2] + sdata[3]);
}

// ---------------- helpers ----------------
// v_cvt_pk_bf16_f32: dst = (bf16(b)<<16) | bf16(a), RNE. No builtin on gfx950.
__device__ inline unsigned int cvt_pk_bf16(float a, float b) {
    unsigned int r;
    asm("v_cvt_pk_bf16_f32 %0, %1, %2" : "=v"(r) : "v"(a), "v"(b));
    return r;
}
// Split (a,b) into packed-bf16 hi dword + lo dword (x ~= hi + lo, ~16-bit mantissa).
__device__ inline void split_pair(float a, float b, unsigned int& h, unsigned int& l) {
    h = cvt_pk_bf16(a, b);
    float ra = a - __builtin_bit_cast(float, h << 16);
    float rb = b - __builtin_bit_cast(float, h & 0xffff0000u);
    l = cvt_pk_bf16(ra, rb);
}
__device__ inline short8 frag_of(unsigned int u0, unsigned int u1,
                                 unsigned int u2, unsigned int u3) {
    uint4v u = {u0, u1, u2, u3};
    return __builtin_bit_cast(short8, u);
}
// 8 consecutive-k floats -> hi/lo bf16x8 fragments.
__device__ inline void split_frag(f32x4 a, f32x4 b, short8& hi, short8& lo) {
    unsigned int h0, h1, h2, h3, l0, l1, l2, l3;
    split_pair(a.x, a.y, h0, l0);
    split_pair(a.z, a.w, h1, l1);
    split_pair(b.x, b.y, h2, l2);
    split_pair(b.z, b.w, h3, l3);
    hi = frag_of(h0, h1, h2, h3);
    lo = frag_of(l0, l1, l2, l3);
}
// 4-term split product: full ~f32 accuracy (hh + hl + lh + ll), f32 accumulate.
__device__ inline f32x4 mfma4(short8 wh, short8 wl, short8 bh, short8 bl, f32x4 acc) {
    acc = __builtin_amdgcn_mfma_f32_16x16x32_bf16(wh, bh, acc, 0, 0, 0);
    acc = __builtin_amdgcn_mfma_f32_16x16x32_bf16(wh, bl, acc, 0, 0, 0);
    acc = __builtin_amdgcn_mfma_f32_16x16x32_bf16(wl, bh, acc, 0, 0, 0);
    acc = __builtin_amdgcn_mfma_f32_16x16x32_bf16(wl, bl, acc, 0, 0, 0);
    return acc;
}
__device__ inline f32x4 relu4(f32x4 v) {
    v.x = fmaxf(v.x, 0.f); v.y = fmaxf(v.y, 0.f);
    v.z = fmaxf(v.z, 0.f); v.w = fmaxf(v.w, 0.f);
    return v;
}
// D-frag (transposed GEMM) -> next layer's B-frag, via 8 ds_bpermute.
// Input: lane (m=l&15, q=l>>4) holds channels {4q..4q+3} (v0) and {16+4q..} (v1)
// of pixel m. Output: lane needs packed channels {8q..8q+7} of the SAME pixel.
// 4 rounds/array; round sources are lanes m+16*bitrev2(q) and ^1 (verified by hand).
__device__ inline void transpose_to_bfrag(f32x4 v0, f32x4 v1, int i1, int i2,
                                          bool oddq, bool lowq,
                                          short8& bh, short8& bl) {
    unsigned int Ah, Al, Bh, Bl, Ch, Cl, Dh, Dl;
    split_pair(v0.x, v0.y, Ah, Al);   // ch (4q, 4q+1)
    split_pair(v0.z, v0.w, Bh, Bl);   // ch (4q+2, 4q+3)
    split_pair(v1.x, v1.y, Ch, Cl);   // ch (16+4q, 16+4q+1)
    split_pair(v1.z, v1.w, Dh, Dl);   // ch (16+4q+2, 16+4q+3)
    int f1h = __builtin_amdgcn_ds_bpermute(i1, (int)(oddq ? Ch : Ah));
    int f2h = __builtin_amdgcn_ds_bpermute(i2, (int)(oddq ? Ah : Ch));
    int f3h = __builtin_amdgcn_ds_bpermute(i1, (int)(oddq ? Dh : Bh));
    int f4h = __builtin_amdgcn_ds_bpermute(i2, (int)(oddq ? Bh : Dh));
    int f1l = __builtin_amdgcn_ds_bpermute(i1, (int)(oddq ? Cl : Al));
    int f2l = __builtin_amdgcn_ds_bpermute(i2, (int)(oddq ? Al : Cl));
    int f3l = __builtin_amdgcn_ds_bpermute(i1, (int)(oddq ? Dl : Bl));
    int f4l = __builtin_amdgcn_ds_bpermute(i2, (int)(oddq ? Bl : Dl));
    // frag = (T0, T1, T2, T3) = packed ch pairs (8q,8q+1)..(8q+6,8q+7)
    bh = frag_of(lowq ? (unsigned)f1h : (unsigned)f2h, lowq ? (unsigned)f3h : (unsigned)f4h,
                 lowq ? (unsigned)f2h : (unsigned)f1h, lowq ? (unsigned)f4h : (unsigned)f3h);
    bl = frag_of(lowq ? (unsigned)f1l : (unsigned)f2l, lowq ? (unsigned)f3l : (unsigned)f4l,
                 lowq ? (unsigned)f2l : (unsigned)f1l, lowq ? (unsigned)f4l : (unsigned)f3l);
}

// ---------------- kernel 2: fused NCA step, MLP on MFMA ----------------
// R6: VALU path is structurally capped (~200us best case at sustained rates;
// 3 rounds of register-restructure all neutral at 328us). The MLP is GEMM-
// shaped -> matrix cores. Transposed orientation (D = W * P, pixels = columns)
// so D's lane layout matches the next layer's B-frag except a channel shuffle
// among lanes {l, l^16, l^32} done with ds_bpermute. Per wave (64 pixels):
// 80 MFMAs, ~41us chip-wide on the matrix pipe; predicted wall is now the
// LDS pipe (~130-150us): sobel reads + B1 staging + bpermutes.
__global__ __launch_bounds__(256)
void nca_fused_kernel(const float* __restrict__ x,
                      const float* __restrict__ w1, const float* __restrict__ b1,
                      const float* __restrict__ w2, const float* __restrict__ b2,
                      const float* __restrict__ w3, const float* __restrict__ b3,
                      const float* __restrict__ growth,
                      const int* __restrict__ alive_cnt,
                      float* __restrict__ out) {
    __shared__ float tile[kC][THP][TWP];                    // 12672 B
    // Perceive staged as B-matrix [pixel][k] bf16 hi/lo, per wave.
    // Row stride 20 dw (80 B): 16B-aligned for b128, 5*t%8 spreads bank quads.
    __shared__ __align__(16) unsigned int s_hi[4][64][20];  // 20480 B
    __shared__ __align__(16) unsigned int s_lo[4][64][20];  // 20480 B
    __shared__ __align__(16) float s_d[4][64][8];           // 8192 B -> total 61824 B

    const int w0 = blockIdx.x * TW;
    const int h0 = blockIdx.y * TH;
    const int b  = blockIdx.z;
    const int tid = threadIdx.x;
    const int lane = tid & 63;
    const int wv = tid >> 6;
    const int m = lane & 15;        // MFMA col (pixel within n-tile)
    const int q = lane >> 4;        // k-slice group
    const bool oddq = (q & 1) != 0;
    const bool lowq = q < 2;
    const int brq = ((q & 1) << 1) | (q >> 1);     // bitrev2(q)
    const int i1 = (m + 16 * brq) << 2;            // bpermute byte indices
    const int i2 = (m + 16 * (brq ^ 1)) << 2;
    const float* xb = x + b * kBS;

    // ---- weights -> persistent A-fragments (A row = out-ch, k-slice = q*8) ----
    f32x4 zero4 = {0.f, 0.f, 0.f, 0.f};
    short8 w1h[2], w1l[2], w2h[2], w2l[2], w3h, w3l;
    f32x4 bias1[2], bias2[2], bias3;
#pragma unroll
    for (int mo = 0; mo < 2; ++mo) {
        int o = mo * 16 + m;
        int off = (q < 3) ? (o * 24 + q * 8) : 0;   // K=24 padded to 32; q==3 is pad
        f32x4 wa = *(const f32x4*)(w1 + off);
        f32x4 wb = *(const f32x4*)(w1 + off + 4);
        if (q == 3) { wa = zero4; wb = zero4; }
        split_frag(wa, wb, w1h[mo], w1l[mo]);
        f32x4 wc = *(const f32x4*)(w2 + o * 32 + q * 8);
        f32x4 wd = *(const f32x4*)(w2 + o * 32 + q * 8 + 4);
        split_frag(wc, wd, w2h[mo], w2l[mo]);
        bias1[mo] = *(const f32x4*)(b1 + mo * 16 + q * 4);
        bias2[mo] = *(const f32x4*)(b2 + mo * 16 + q * 4);
    }
    {
        int off3 = (m < 8) ? (m * 32 + q * 8) : 0;  // w3: rows 8..15 are pad
        f32x4 wa = *(const f32x4*)(w3 + off3);
        f32x4 wb = *(const f32x4*)(w3 + off3 + 4);
        if (m >= 8) { wa = zero4; wb = zero4; }
        split_frag(wa, wb, w3h, w3l);
        bias3 = zero4;
        if (lowq) bias3 = *(const f32x4*)(b3 + q * 4);
    }

    // ---- stage input tile ----
    constexpr int TILE_N = kC * THP * TWP;
    for (int i = tid; i < TILE_N; i += 256) {
        int c  = i / (THP * TWP);
        int rr = i - c * (THP * TWP);
        int th = rr / TWP;
        int tw = rr - th * TWP;
        int gh = h0 + th - 1;
        int gw = w0 + tw - 1;
        float v = 0.0f;
        if ((unsigned)gh < (unsigned)kH && (unsigned)gw < (unsigned)kW)
            v = xb[c * kHW + gh * kW + gw];
        (&tile[0][0][0])[i] = v;
    }
    __syncthreads();

    // ---- phase A: per-thread perceive (sobel) + stage hi/lo B1 ----
    const int ww = lane;   // one wave per tile row; lane = pixel col
    const int hh = wv;
    float p[24];
    int nalive = 0;
#pragma unroll
    for (int c = 0; c < kC; ++c) {
        float a00 = tile[c][hh][ww],     a01 = tile[c][hh][ww + 1],     a02 = tile[c][hh][ww + 2];
        float a10 = tile[c][hh + 1][ww], a11 = tile[c][hh + 1][ww + 1], a12 = tile[c][hh + 1][ww + 2];
        float a20 = tile[c][hh + 2][ww], a21 = tile[c][hh + 2][ww + 1], a22 = tile[c][hh + 2][ww + 2];
        p[c]      = a11;
        p[8 + c]  = (a02 - a00) + 2.0f * (a12 - a10) + (a22 - a20);   // sobel_x
        p[16 + c] = (a20 - a00) + 2.0f * (a21 - a01) + (a22 - a02);   // sobel_y
        if (c == 3) {
            nalive = (a00 > 0.1f) + (a01 > 0.1f) + (a02 > 0.1f)
                   + (a10 > 0.1f) + (a11 > 0.1f) + (a12 > 0.1f)
                   + (a20 > 0.1f) + (a21 > 0.1f) + (a22 > 0.1f);
        }
    }
#pragma unroll
    for (int gg = 0; gg < 3; ++gg) {   // k groups 0..2 (k=8g..8g+7); group 3 = pad
        unsigned int ha, hb, hc, hd, la, lb, lc, ld;
        split_pair(p[8 * gg + 0], p[8 * gg + 1], ha, la);
        split_pair(p[8 * gg + 2], p[8 * gg + 3], hb, lb);
        split_pair(p[8 * gg + 4], p[8 * gg + 5], hc, lc);
        split_pair(p[8 * gg + 6], p[8 * gg + 7], hd, ld);
        uint4v uh = {ha, hb, hc, hd};
        uint4v ul = {la, lb, lc, ld};
        *(uint4v*)&s_hi[wv][lane][gg * 4] = uh;
        *(uint4v*)&s_lo[wv][lane][gg * 4] = ul;
    }
    {
        uint4v z = {0u, 0u, 0u, 0u};
        *(uint4v*)&s_hi[wv][lane][12] = z;   // k=24..31 pad must be zero
        *(uint4v*)&s_lo[wv][lane][12] = z;
    }
    // Same-wave producer/consumer for s_hi/s_lo/s_d: no __syncthreads needed,
    // compiler-inserted lgkmcnt waits order the ds ops.

    // ---- phase B: 3-layer MLP on matrix cores, 16 pixels per np-tile ----
#pragma unroll
    for (int np = 0; np < 4; ++np) {
        const int r = np * 16 + m;   // this lane's B-column pixel (within wave row)
        short8 bh = __builtin_bit_cast(short8, *(const uint4v*)&s_hi[wv][r][q * 4]);
        short8 bl = __builtin_bit_cast(short8, *(const uint4v*)&s_lo[wv][r][q * 4]);
        // layer 1: D = W1[32x24] * P  (acc rows = out-ch 4q+r (+16 for mo=1), col = pixel)
        f32x4 acc0 = bias1[0], acc1 = bias1[1];
        acc0 = mfma4(w1h[0], w1l[0], bh, bl, acc0);
        acc1 = mfma4(w1h[1], w1l[1], bh, bl, acc1);
        acc0 = relu4(acc0); acc1 = relu4(acc1);
        short8 b2fh, b2fl;
        transpose_to_bfrag(acc0, acc1, i1, i2, oddq, lowq, b2fh, b2fl);
        // layer 2: D = W2[32x32] * H1
        f32x4 acc2a = bias2[0], acc2b = bias2[1];
        acc2a = mfma4(w2h[0], w2l[0], b2fh, b2fl, acc2a);
        acc2b = mfma4(w2h[1], w2l[1], b2fh, b2fl, acc2b);
        acc2a = relu4(acc2a); acc2b = relu4(acc2b);
        short8 b3fh, b3fl;
        transpose_to_bfrag(acc2a, acc2b, i1, i2, oddq, lowq, b3fh, b3fl);
        // layer 3: D = W3[8x32] * H2 (rows 8..15 are zero pad)
        f32x4 acc3 = bias3;
        acc3 = mfma4(w3h, w3l, b3fh, b3fl, acc3);
        if (lowq) {                     // rows 0..7 only: ch q*4+reg
            *(f32x4*)&s_d[wv][r][q * 4] = acc3;
        }
    }

    // ---- epilogue: per-thread pixel (hh, ww) ----
    f32x4 dA = *(const f32x4*)&s_d[wv][lane][0];
    f32x4 dB = *(const f32x4*)&s_d[wv][lane][4];
    float dv[8] = {dA.x, dA.y, dA.z, dA.w, dB.x, dB.y, dB.z, dB.w};
    const float g = growth[0];  // GROWTH_BOOST == 1.0
    const float ratio = (float)(*alive_cnt) * (1.0f / 4194304.0f);
    const float boost = (ratio < 0.2f && nalive > 0) ? 0.2f : 0.0f;
    float* ob = out + b * kBS + (h0 + hh) * kW + (w0 + ww);
#pragma unroll
    for (int c = 0; c < kC; ++c) {
        float v = p[c] + dv[c] * g + ((c == 3) ? boost : 0.0f);
        const float lo = (c == 3) ? 0.0f : -1.0f;
        v = fminf(fmaxf(v, lo), 1.0f);
        ob[c * kHW] = v;
    }
}

}  // namespace

extern "C" void kernel_launch(void* const* d_in, const int* in_sizes, int n_in,
                              void* d_out, int out_size, void* d_ws, size_t ws_size,
                              hipStream_t stream) {
    const float* x  = (const float*)d_in[0];
    const float* w1 = (const float*)d_in[1];
    const float* b1 = (const float*)d_in[2];
    const float* w2 = (const float*)d_in[3];
    const float* b2 = (const float*)d_in[4];
    const float* w3 = (const float*)d_in[5];
    const float* b3 = (const float*)d_in[6];
    const float* gr = (const float*)d_in[7];
    float* out = (float*)d_out;
    int* cnt = (int*)d_ws;  // ws is re-poisoned 0xAA each launch -> must zero

    hipMemsetAsync(cnt, 0, sizeof(int), stream);
    alive_count_kernel<<<2048, 256, 0, stream>>>(x, cnt);
    dim3 grid(kW / TW, kH / TH, kB);
    nca_fused_kernel<<<grid, 256, 0, stream>>>(x, w1, b1, w2, b2, w3, b3, gr, cnt, out);
}

// Round 4
// 473.292 us; speedup vs baseline: 1.1957x; 1.1957x over previous
//
#include <hip/hip_runtime.h>

namespace {

typedef __attribute__((ext_vector_type(8))) short short8;   // 8 bf16 (MFMA A/B frag)
typedef __attribute__((ext_vector_type(4))) float f32x4;    // MFMA C/D frag
typedef __attribute__((ext_vector_type(4))) unsigned int uint4v;

constexpr int kH = 512, kW = 512, kB = 16, kC = 8;
constexpr int kHW = kH * kW;
constexpr int kBS = kC * kHW;
constexpr int TW = 64, TH = 4;
constexpr int TWP = TW + 2, THP = TH + 2;

// ---------------- kernel 1: global alive count ----------------
__global__ __launch_bounds__(256)
void alive_count_kernel(const float* __restrict__ x, int* __restrict__ cnt) {
    __shared__ int sdata[4];
    const int tid = threadIdx.x;
    const int total4 = kB * kHW / 4;
    int idx = blockIdx.x * 256 + tid;
    const int stride = gridDim.x * 256;
    int local = 0;
    const float4* x4 = (const float4*)x;
    for (int i = idx; i < total4; i += stride) {
        int b = i >> 16;
        int off = i & 65535;
        float4 v = x4[(size_t)b * (kBS / 4) + (3 * kHW / 4) + off];
        local += (v.x > 0.1f) + (v.y > 0.1f) + (v.z > 0.1f) + (v.w > 0.1f);
    }
    for (int off = 32; off > 0; off >>= 1)
        local += __shfl_down(local, off, 64);
    if ((tid & 63) == 0) sdata[tid >> 6] = local;
    __syncthreads();
    if (tid == 0) atomicAdd(cnt, sdata[0] + sdata[1] + sdata[2] + sdata[3]);
}

// ---------------- helpers ----------------
// v_cvt_pk_bf16_f32: dst = (bf16(b)<<16) | bf16(a), RNE. No builtin on gfx950.
__device__ inline unsigned int cvt_pk_bf16(float a, float b) {
    unsigned int r;
    asm("v_cvt_pk_bf16_f32 %0, %1, %2" : "=v"(r) : "v"(a), "v"(b));
    return r;
}
// Split (a,b) into packed-bf16 hi dword + lo dword (x ~= hi + lo, ~16-bit mantissa).
__device__ inline void split_pair(float a, float b, unsigned int& h, unsigned int& l) {
    h = cvt_pk_bf16(a, b);
    float ra = a - __builtin_bit_cast(float, h << 16);
    float rb = b - __builtin_bit_cast(float, h & 0xffff0000u);
    l = cvt_pk_bf16(ra, rb);
}
__device__ inline short8 frag_of(unsigned int u0, unsigned int u1,
                                 unsigned int u2, unsigned int u3) {
    uint4v u = {u0, u1, u2, u3};
    return __builtin_bit_cast(short8, u);
}
// Two f32x4 (8 consecutive-k values) -> hi/lo bf16x8 fragments.
__device__ inline void split_frag(f32x4 a, f32x4 b, short8& hi, short8& lo) {
    unsigned int h0, h1, h2, h3, l0, l1, l2, l3;
    split_pair(a.x, a.y, h0, l0);
    split_pair(a.z, a.w, h1, l1);
    split_pair(b.x, b.y, h2, l2);
    split_pair(b.z, b.w, h3, l3);
    hi = frag_of(h0, h1, h2, h3);
    lo = frag_of(l0, l1, l2, l3);
}
// 3-term split product: hh + hl + lh (ll term ~2^-18 relative -- negligible).
__device__ inline f32x4 mfma3(short8 wh, short8 wl, short8 bh, short8 bl, f32x4 acc) {
    acc = __builtin_amdgcn_mfma_f32_16x16x32_bf16(wh, bh, acc, 0, 0, 0);
    acc = __builtin_amdgcn_mfma_f32_16x16x32_bf16(wh, bl, acc, 0, 0, 0);
    acc = __builtin_amdgcn_mfma_f32_16x16x32_bf16(wl, bh, acc, 0, 0, 0);
    return acc;
}
__device__ inline f32x4 relu4(f32x4 v) {
    v.x = fmaxf(v.x, 0.f); v.y = fmaxf(v.y, 0.f);
    v.z = fmaxf(v.z, 0.f); v.w = fmaxf(v.w, 0.f);
    return v;
}

// ---------------- kernel 2: fused NCA step, MLP on MFMA ----------------
// R7: sigma-permuted weight rows (sigma(4q+i)=8q+i, sigma(16+4q+i)=8q+4+i) make
// each layer's D-frag channel set exactly the next layer's B-frag k-slice:
// inter-layer transpose = 4 cvt_pk packs (was 8 ds_bpermute + 16 cndmask x2).
// LDS 62KB -> 37.4KB (stride-12 staging, no k-pad: q=3 A-frags are zero so
// B k=24..31 may be garbage; s_d aliases dead tile[] after a barrier)
// -> 4 blocks/CU. 3-term MFMA (drop ll). Live floats ~90 -> no AGPR shuffle.
__global__ __launch_bounds__(256)
void nca_fused_kernel(const float* __restrict__ x,
                      const float* __restrict__ w1, const float* __restrict__ b1,
                      const float* __restrict__ w2, const float* __restrict__ b2,
                      const float* __restrict__ w3, const float* __restrict__ b3,
                      const float* __restrict__ growth,
                      const int* __restrict__ alive_cnt,
                      float* __restrict__ out) {
    __shared__ __align__(16) float tile[kC][THP][TWP];      // 12672 B; aliased by s_d in phase B
    // Perceive staging [wave][pixel*12 + kdword], stride 12 dwords (48B).
    // +4 tail dwords keep q=3's garbage b128 read in bounds (row 63, dw 12..15).
    __shared__ __align__(16) unsigned int s_hi[4][64 * 12 + 4];  // 12352 B
    __shared__ __align__(16) unsigned int s_lo[4][64 * 12 + 4];  // 12352 B -> total 37376 B

    const int w0 = blockIdx.x * TW;
    const int h0 = blockIdx.y * TH;
    const int b  = blockIdx.z;
    const int tid = threadIdx.x;
    const int lane = tid & 63;
    const int wv = tid >> 6;
    const int m = lane & 15;        // MFMA col (pixel within np-tile) / A row
    const int q = lane >> 4;        // k-slice group
    const float* xb = x + b * kBS;

    // sigma-permuted stored rows: stored row m (tile0) = true row s0, tile1 = s1.
    const int s0 = ((m >> 2) << 3) + (m & 3);   // sigma0(m) = 8*(m/4) + m%4
    const int s1 = s0 + 4;

    // ---- weights -> persistent A-fragments ----
    f32x4 zero4 = {0.f, 0.f, 0.f, 0.f};
    short8 w1h[2], w1l[2], w2h[2], w2l[2], w3h, w3l;
    {
        f32x4 a = zero4, bb = zero4;
        if (q < 3) { a = *(const f32x4*)(w1 + s0 * 24 + q * 8); bb = *(const f32x4*)(w1 + s0 * 24 + q * 8 + 4); }
        split_frag(a, bb, w1h[0], w1l[0]);
        a = zero4; bb = zero4;
        if (q < 3) { a = *(const f32x4*)(w1 + s1 * 24 + q * 8); bb = *(const f32x4*)(w1 + s1 * 24 + q * 8 + 4); }
        split_frag(a, bb, w1h[1], w1l[1]);
        a = *(const f32x4*)(w2 + s0 * 32 + q * 8); bb = *(const f32x4*)(w2 + s0 * 32 + q * 8 + 4);
        split_frag(a, bb, w2h[0], w2l[0]);
        a = *(const f32x4*)(w2 + s1 * 32 + q * 8); bb = *(const f32x4*)(w2 + s1 * 32 + q * 8 + 4);
        split_frag(a, bb, w2h[1], w2l[1]);
        a = zero4; bb = zero4;
        if (m < 8) { a = *(const f32x4*)(w3 + m * 32 + q * 8); bb = *(const f32x4*)(w3 + m * 32 + q * 8 + 4); }
        split_frag(a, bb, w3h, w3l);
    }
    // Biases in sigma space: D reg i of tile0 = true ch 8q+i; tile1 = 8q+4+i.
    const f32x4 bias1a = *(const f32x4*)(b1 + q * 8);
    const f32x4 bias1b = *(const f32x4*)(b1 + q * 8 + 4);
    const f32x4 bias2a = *(const f32x4*)(b2 + q * 8);
    const f32x4 bias2b = *(const f32x4*)(b2 + q * 8 + 4);
    const f32x4 bias3  = (q < 2) ? *(const f32x4*)(b3 + q * 4) : zero4;

    // ---- stage input tile ----
    constexpr int TILE_N = kC * THP * TWP;
    for (int i = tid; i < TILE_N; i += 256) {
        int c  = i / (THP * TWP);
        int rr = i - c * (THP * TWP);
        int th = rr / TWP;
        int tw = rr - th * TWP;
        int gh = h0 + th - 1;
        int gw = w0 + tw - 1;
        float v = 0.0f;
        if ((unsigned)gh < (unsigned)kH && (unsigned)gw < (unsigned)kW)
            v = xb[c * kHW + gh * kW + gw];
        (&tile[0][0][0])[i] = v;
    }
    __syncthreads();

    // ---- phase A: per-thread perceive (channel pairs) + stage hi/lo ----
    const int ww = lane;
    const int hh = wv;
    float pc[8];
    unsigned int hi[12], lo[12];
    int nalive = 0;
#pragma unroll
    for (int j = 0; j < 4; ++j) {
        const int c0 = 2 * j, c1 = c0 + 1;
        float b00 = tile[c0][hh][ww],     b01 = tile[c0][hh][ww + 1],     b02 = tile[c0][hh][ww + 2];
        float b10 = tile[c0][hh + 1][ww], b11 = tile[c0][hh + 1][ww + 1], b12 = tile[c0][hh + 1][ww + 2];
        float b20 = tile[c0][hh + 2][ww], b21 = tile[c0][hh + 2][ww + 1], b22 = tile[c0][hh + 2][ww + 2];
        float c00 = tile[c1][hh][ww],     c01 = tile[c1][hh][ww + 1],     c02 = tile[c1][hh][ww + 2];
        float c10 = tile[c1][hh + 1][ww], c11 = tile[c1][hh + 1][ww + 1], c12 = tile[c1][hh + 1][ww + 2];
        float c20 = tile[c1][hh + 2][ww], c21 = tile[c1][hh + 2][ww + 1], c22 = tile[c1][hh + 2][ww + 2];
        float sx0 = (b02 - b00) + 2.0f * (b12 - b10) + (b22 - b20);
        float sy0 = (b20 - b00) + 2.0f * (b21 - b01) + (b22 - b02);
        float sx1 = (c02 - c00) + 2.0f * (c12 - c10) + (c22 - c20);
        float sy1 = (c20 - c00) + 2.0f * (c21 - c01) + (c22 - c02);
        pc[c0] = b11; pc[c1] = c11;
        if (c1 == 3) {
            nalive = (c00 > 0.1f) + (c01 > 0.1f) + (c02 > 0.1f)
                   + (c10 > 0.1f) + (c11 > 0.1f) + (c12 > 0.1f)
                   + (c20 > 0.1f) + (c21 > 0.1f) + (c22 > 0.1f);
        }
        split_pair(b11, c11, hi[j],     lo[j]);       // centers: k-pair (c0,c1)
        split_pair(sx0, sx1, hi[4 + j], lo[4 + j]);   // sobel_x: k-pair (8+c0, 8+c1)
        split_pair(sy0, sy1, hi[8 + j], lo[8 + j]);   // sobel_y: k-pair (16+c0, 16+c1)
    }
    {
        unsigned int* hb = &s_hi[wv][lane * 12];
        unsigned int* lb = &s_lo[wv][lane * 12];
        uint4v v0 = {hi[0], hi[1], hi[2], hi[3]};
        uint4v v1 = {hi[4], hi[5], hi[6], hi[7]};
        uint4v v2 = {hi[8], hi[9], hi[10], hi[11]};
        *(uint4v*)hb = v0; *(uint4v*)(hb + 4) = v1; *(uint4v*)(hb + 8) = v2;
        uint4v u0 = {lo[0], lo[1], lo[2], lo[3]};
        uint4v u1 = {lo[4], lo[5], lo[6], lo[7]};
        uint4v u2 = {lo[8], lo[9], lo[10], lo[11]};
        *(uint4v*)lb = u0; *(uint4v*)(lb + 4) = u1; *(uint4v*)(lb + 8) = u2;
    }
    // All tile[] reads are done; s_d may now alias tile. Barrier covers all waves.
    __syncthreads();
    float* s_d = &tile[0][0][0];   // [wv*64 + pixel]*12 + ch, stride 12 floats

    // ---- phase B: 3-layer MLP on matrix cores, 16 pixels per np-tile ----
#pragma unroll
    for (int np = 0; np < 4; ++np) {
        const int r = np * 16 + m;
        // q==3 reads k=24..31 garbage; zeroed A-frags null its contribution.
        short8 bh = __builtin_bit_cast(short8, *(const uint4v*)&s_hi[wv][r * 12 + q * 4]);
        short8 bl = __builtin_bit_cast(short8, *(const uint4v*)&s_lo[wv][r * 12 + q * 4]);
        // layer 1 (sigma rows): lane gets true-ch {8q..8q+7} of pixel r
        f32x4 acc0 = bias1a, acc1 = bias1b;
        acc0 = mfma3(w1h[0], w1l[0], bh, bl, acc0);
        acc1 = mfma3(w1h[1], w1l[1], bh, bl, acc1);
        acc0 = relu4(acc0); acc1 = relu4(acc1);
        short8 b2h, b2l;
        split_frag(acc0, acc1, b2h, b2l);   // = B-frag k-slice {8q..8q+7}
        // layer 2 (sigma rows, natural cols)
        f32x4 acc2a = bias2a, acc2b = bias2b;
        acc2a = mfma3(w2h[0], w2l[0], b2h, b2l, acc2a);
        acc2b = mfma3(w2h[1], w2l[1], b2h, b2l, acc2b);
        acc2a = relu4(acc2a); acc2b = relu4(acc2b);
        short8 b3h, b3l;
        split_frag(acc2a, acc2b, b3h, b3l);
        // layer 3 (natural rows 0..7, pad 8..15 zeroed)
        f32x4 acc3 = bias3;
        acc3 = mfma3(w3h, w3l, b3h, b3l, acc3);
        if (q < 2)
            *(f32x4*)&s_d[(wv * 64 + r) * 12 + q * 4] = acc3;   // d-ch {4q..4q+3}
    }

    // ---- epilogue: per-thread pixel (hh, ww); same-wave LDS ordering via lgkmcnt ----
    f32x4 dA = *(const f32x4*)&s_d[(wv * 64 + lane) * 12];
    f32x4 dB = *(const f32x4*)&s_d[(wv * 64 + lane) * 12 + 4];
    float dv[8] = {dA.x, dA.y, dA.z, dA.w, dB.x, dB.y, dB.z, dB.w};
    const float g = growth[0];  // GROWTH_BOOST == 1.0
    const float ratio = (float)(*alive_cnt) * (1.0f / 4194304.0f);
    const float boost = (ratio < 0.2f && nalive > 0) ? 0.2f : 0.0f;
    float* ob = out + b * kBS + (h0 + hh) * kW + (w0 + ww);
#pragma unroll
    for (int c = 0; c < kC; ++c) {
        float v = pc[c] + dv[c] * g + ((c == 3) ? boost : 0.0f);
        const float lo2 = (c == 3) ? 0.0f : -1.0f;
        v = fminf(fmaxf(v, lo2), 1.0f);
        ob[c * kHW] = v;
    }
}

}  // namespace

extern "C" void kernel_launch(void* const* d_in, const int* in_sizes, int n_in,
                              void* d_out, int out_size, void* d_ws, size_t ws_size,
                              hipStream_t stream) {
    const float* x  = (const float*)d_in[0];
    const float* w1 = (const float*)d_in[1];
    const float* b1 = (const float*)d_in[2];
    const float* w2 = (const float*)d_in[3];
    const float* b2 = (const float*)d_in[4];
    const float* w3 = (const float*)d_in[5];
    const float* b3 = (const float*)d_in[6];
    const float* gr = (const float*)d_in[7];
    float* out = (float*)d_out;
    int* cnt = (int*)d_ws;  // ws is re-poisoned 0xAA each launch -> must zero

    hipMemsetAsync(cnt, 0, sizeof(int), stream);
    alive_count_kernel<<<2048, 256, 0, stream>>>(x, cnt);
    dim3 grid(kW / TW, kH / TH, kB);
    nca_fused_kernel<<<grid, 256, 0, stream>>>(x, w1, b1, w2, b2, w3, b3, gr, cnt, out);
}